// Round 5
// baseline (322.057 us; speedup 1.0000x reference)
//
#include <hip/hip_runtime.h>

// ---------------------------------------------------------------------------
// TPA attention, factorized to GQA flash attention.
// B=1, S=2048, HID=2048, H=16, KVH=8, D=128, QR=6, KR=2, VR=2
// ---------------------------------------------------------------------------

constexpr int SEQ   = 2048;
constexpr int HIDN  = 2048;
constexpr int NHEAD = 16;
constexpr int NKVH  = 8;
constexpr int DH    = 128;
constexpr int NCOLS = 1408;   // 96 Aq | 16 Ak | 16 Av | 768 Bq | 256 Bk | 256 Bv

typedef __bf16 bf16x8 __attribute__((ext_vector_type(8)));
typedef float  f32x4  __attribute__((ext_vector_type(4)));

#define MFMA(a, b, c) __builtin_amdgcn_mfma_f32_16x16x32_bf16((a), (b), (c), 0, 0, 0)

__device__ __forceinline__ void gload_lds16(const void* g, void* l) {
  __builtin_amdgcn_global_load_lds(
      (const __attribute__((address_space(1))) void*)g,
      (__attribute__((address_space(3))) void*)l, 16, 0, 0);
}

// ---- pack / convert -------------------------------------------------------

__global__ __launch_bounds__(256) void k_cvt_bf16(const float* __restrict__ x,
                                                  __bf16* __restrict__ y, int n) {
  int i = blockIdx.x * 256 + threadIdx.x;
  if (i < n) y[i] = (__bf16)x[i];
}

// W_all^T [1408][2048] bf16 so the GEMM B-operand reads K-contiguous rows.
__global__ __launch_bounds__(256) void k_pack_wall(
    const float* __restrict__ WAq, const float* __restrict__ WAk,
    const float* __restrict__ WAv, const float* __restrict__ WBq,
    const float* __restrict__ WBk, const float* __restrict__ WBv,
    __bf16* __restrict__ WT) {
  int i = blockIdx.x * 256 + threadIdx.x;  // i < 1408*2048
  int c = i >> 11, k = i & 2047;
  float v;
  if (c < 96)        v = WAq[k * 96 + c];
  else if (c < 112)  v = WAk[k * 16 + (c - 96)];
  else if (c < 128)  v = WAv[k * 16 + (c - 112)];
  else if (c < 896)  v = WBq[k * 768 + (c - 128)];
  else if (c < 1152) v = WBk[k * 256 + (c - 896)];
  else               v = WBv[k * 256 + (c - 1152)];
  WT[i] = (__bf16)v;
}

// Wo^T [2048][2048] bf16 via LDS tile transpose (coalesced both sides).
__global__ __launch_bounds__(256) void k_pack_wo(const float* __restrict__ Wo,
                                                 __bf16* __restrict__ WoT) {
  __shared__ float t[32][33];
  int bn = blockIdx.x * 32, bk = blockIdx.y * 32;
  int tx = threadIdx.x & 31, ty = threadIdx.x >> 5;  // ty 0..7
  for (int j = 0; j < 32; j += 8)
    t[ty + j][tx] = Wo[(size_t)(bk + ty + j) * HIDN + bn + tx];
  __syncthreads();
  for (int j = 0; j < 32; j += 8)
    WoT[(size_t)(bn + ty + j) * HIDN + bk + tx] = (__bf16)t[tx][ty + j];
}

// ---- GEMM: C[M][N] = A[M][K] * BT[N][K]^T, bf16 in, f32 out ---------------
// 128(M)x64(N) tile, 4 waves (2x2), BK=32, global_load_lds staging.

__global__ __launch_bounds__(256) void k_gemm_bt(const __bf16* __restrict__ A,
                                                 const __bf16* __restrict__ BT,
                                                 float* __restrict__ C,
                                                 int M, int N, int K) {
  __shared__ __bf16 As[4096];  // [128 rows][32 k] linear
  __shared__ __bf16 Bs[2048];  // [64 cols][32 k] linear
  const int tid = threadIdx.x;
  const int w = tid >> 6, lane = tid & 63;
  const int lhi = lane >> 4, llo = lane & 15;
  const int wr = w >> 1, wc = w & 1;
  const int brow = blockIdx.y * 128, bcol = blockIdx.x * 64;
  const int rA = lane >> 2, kA = (lane & 3) * 8;  // lane -> (row-in-seg, k-seg)

  f32x4 acc[4][2];
#pragma unroll
  for (int m = 0; m < 4; m++)
#pragma unroll
    for (int n = 0; n < 2; n++) acc[m][n] = (f32x4){0.f, 0.f, 0.f, 0.f};

  for (int k0 = 0; k0 < K; k0 += 32) {
#pragma unroll
    for (int i = 0; i < 2; i++) {
      int seg = w * 2 + i;           // 8 segs of 1KB for A
      int row = seg * 16 + rA;
      gload_lds16(A + (size_t)(brow + row) * K + k0 + kA, &As[seg * 512]);
    }
    gload_lds16(BT + (size_t)(bcol + w * 16 + rA) * K + k0 + kA, &Bs[w * 512]);
    __syncthreads();
    bf16x8 af[4], bfr[2];
#pragma unroll
    for (int m = 0; m < 4; m++)
      af[m] = *(const bf16x8*)&As[(wr * 64 + m * 16 + llo) * 32 + lhi * 8];
#pragma unroll
    for (int n = 0; n < 2; n++)
      bfr[n] = *(const bf16x8*)&Bs[(wc * 32 + n * 16 + llo) * 32 + lhi * 8];
#pragma unroll
    for (int m = 0; m < 4; m++)
#pragma unroll
      for (int n = 0; n < 2; n++) acc[m][n] = MFMA(af[m], bfr[n], acc[m][n]);
    __syncthreads();
  }
#pragma unroll
  for (int m = 0; m < 4; m++)
#pragma unroll
    for (int n = 0; n < 2; n++) {
      int r0 = brow + wr * 64 + m * 16 + lhi * 4;
      int c0 = bcol + wc * 32 + n * 16 + llo;
#pragma unroll
      for (int r = 0; r < 4; r++) C[(size_t)(r0 + r) * N + c0] = acc[m][n][r];
    }
}

// ---- build Q/K/Vt from projections (rope + rank contraction) --------------

__global__ __launch_bounds__(128) void k_build_qkv(const float* __restrict__ P,
                                                   const float* __restrict__ cosT,
                                                   const float* __restrict__ sinT,
                                                   __bf16* __restrict__ Qo,
                                                   __bf16* __restrict__ Ko,
                                                   __bf16* __restrict__ Vto) {
  const int q = blockIdx.x, d = threadIdx.x;  // 128 threads
  __shared__ float Ash[128];                  // Aq(96) | Ak(16) | Av(16)
  const float* row = P + (size_t)q * NCOLS;
  Ash[d] = row[d];
  __syncthreads();
  const int m2 = (d >> 1) * 2;
  const bool odd = d & 1;
  const float c = cosT[q * 64 + (d >> 1)];
  const float s = sinT[q * 64 + (d >> 1)];

  float qacc[16];
#pragma unroll
  for (int h = 0; h < 16; h++) qacc[h] = 0.f;
#pragma unroll
  for (int r = 0; r < 6; r++) {
    float xe = row[128 + r * 128 + m2];
    float xo = row[128 + r * 128 + m2 + 1];
    float br = odd ? (xe * s + xo * c) : (xe * c - xo * s);
#pragma unroll
    for (int h = 0; h < 16; h++) qacc[h] += Ash[h * 6 + r] * br;
  }
#pragma unroll
  for (int h = 0; h < 16; h++)
    Qo[((size_t)h * SEQ + q) * DH + d] = (__bf16)(qacc[h] * 0.08838834764831845f);

  float kacc[8];
#pragma unroll
  for (int g = 0; g < 8; g++) kacc[g] = 0.f;
#pragma unroll
  for (int ss = 0; ss < 2; ss++) {
    float xe = row[896 + ss * 128 + m2];
    float xo = row[896 + ss * 128 + m2 + 1];
    float bs = odd ? (xe * s + xo * c) : (xe * c - xo * s);
#pragma unroll
    for (int g = 0; g < 8; g++) kacc[g] += Ash[96 + g * 2 + ss] * bs;
  }
#pragma unroll
  for (int g = 0; g < 8; g++)
    Ko[((size_t)g * SEQ + q) * DH + d] = (__bf16)kacc[g];

  float vacc[8];
#pragma unroll
  for (int g = 0; g < 8; g++) vacc[g] = 0.f;
#pragma unroll
  for (int u = 0; u < 2; u++) {
    float vu = row[1152 + u * 128 + d];
#pragma unroll
    for (int g = 0; g < 8; g++) vacc[g] += Ash[112 + g * 2 + u] * vu;
  }
#pragma unroll
  for (int g = 0; g < 8; g++)
    Vto[((size_t)g * DH + d) * SEQ + q] = (__bf16)vacc[g];
}

// ---- flash attention: wave-independent + split-KV parts=2 -----------------
// 1024 blocks x 4 waves; each WAVE independently owns (16 q-rows, head, part)
// — no barriers, no K/V LDS (K/V L2-resident with XCD affinity raw&7 = g).
// Balanced decode: the 4 blocks j=4c..4c+3 sharing a CU get bqi {c,31-c,
// 31-c,c} x parts {0,1} -> constant work per CU. Zero-cost prefetch: after
// QK consumes kf, re-issue kf loads for tile t+1 into the SAME registers
// (WAR dep keeps ordering); same for vf after PV — ~300cy compute cover
// each, no extra VGPRs. Fixed-max softmax (softcap bounds scores) => split
// partials merge by pure addition in k_norm.

__global__ __launch_bounds__(256) void k_attn(const __bf16* __restrict__ Q,
                                              const __bf16* __restrict__ Kc,
                                              const __bf16* __restrict__ Vt,
                                              float* __restrict__ AOf0,
                                              float* __restrict__ AOf1,
                                              float* __restrict__ Ls) {
  const int raw = blockIdx.x;          // 0..1023
  const int g = raw & 7;               // XCD affinity
  const int j = raw >> 3;              // 0..127
  const int cu = j >> 2, m = j & 3;
  const int p = m & 1, hh = m >> 1;
  const int h = g * 2 + hh;
  const int bqi = (hh ^ p) ? 31 - cu : cu;
  const int w = threadIdx.x >> 6, lane = threadIdx.x & 63;
  const int lhi = lane >> 4, llo = lane & 15;
  const int q0 = bqi * 64 + w * 16;
  const int nt = (q0 >> 5) + 1;        // causal tiles for these 16 rows
  const int ht = nt >> 1;
  const int t0 = p ? ht : 0;
  const int t1 = p ? nt : ht;

  __shared__ __bf16 Plds[4][512];      // per-wave private 16x32 P tile, swz
  __bf16* Pl = Plds[w];

  const __bf16* Qh = Q  + (size_t)h * SEQ * DH;
  const __bf16* Kg = Kc + (size_t)g * SEQ * DH;
  const __bf16* Vg = Vt + (size_t)g * DH * SEQ;
  float* AOc = p ? AOf1 : AOf0;

  bf16x8 aq[4];
#pragma unroll
  for (int c = 0; c < 4; c++)
    aq[c] = *(const bf16x8*)&Qh[(size_t)(q0 + llo) * DH + c * 32 + lhi * 8];

  f32x4 oacc[8];
  float lsum[4] = {0.f, 0.f, 0.f, 0.f};
#pragma unroll
  for (int n = 0; n < 8; n++) oacc[n] = (f32x4){0.f, 0.f, 0.f, 0.f};

  bf16x8 kf[8], vf[8];
  if (t0 < t1) {
    const int kb = t0 * 32;
#pragma unroll
    for (int c = 0; c < 4; c++) {
      kf[c * 2]     = *(const bf16x8*)&Kg[(size_t)(kb + llo) * DH + c * 32 + lhi * 8];
      kf[c * 2 + 1] = *(const bf16x8*)&Kg[(size_t)(kb + 16 + llo) * DH + c * 32 + lhi * 8];
    }
#pragma unroll
    for (int n = 0; n < 8; n++)
      vf[n] = *(const bf16x8*)&Vg[(size_t)(n * 16 + llo) * SEQ + kb + lhi * 8];
  }

  for (int t = t0; t < t1; t++) {
    const int kb = t * 32;
    f32x4 s0 = {0.f, 0.f, 0.f, 0.f}, s1 = {0.f, 0.f, 0.f, 0.f};
#pragma unroll
    for (int c = 0; c < 4; c++) {
      s0 = MFMA(aq[c], kf[c * 2], s0);
      s1 = MFMA(aq[c], kf[c * 2 + 1], s1);
    }
    if (t + 1 < t1) {   // prefetch next K into same regs (WAR-ordered)
      const int kb2 = kb + 32;
#pragma unroll
      for (int c = 0; c < 4; c++) {
        kf[c * 2]     = *(const bf16x8*)&Kg[(size_t)(kb2 + llo) * DH + c * 32 + lhi * 8];
        kf[c * 2 + 1] = *(const bf16x8*)&Kg[(size_t)(kb2 + 16 + llo) * DH + c * 32 + lhi * 8];
      }
    }
#pragma unroll
    for (int r = 0; r < 4; r++) {
      const int qrow = q0 + lhi * 4 + r;
      const int rho = lhi * 4 + r;
      // w = exp(50*tanh(v/50)) = exp2(72.135 - 144.27/(e^{v/25}+1));
      // range [e^-50, e^50] — f32-safe, exact softmax after normalize.
      float t0e = exp2f(s0[r] * 0.057707802f);
      float t1e = exp2f(s1[r] * 0.057707802f);
      float p0 = exp2f(72.134752f - 144.269504f * __builtin_amdgcn_rcpf(t0e + 1.f));
      float p1 = exp2f(72.134752f - 144.269504f * __builtin_amdgcn_rcpf(t1e + 1.f));
      if (kb + llo > qrow) p0 = 0.f;
      if (kb + 16 + llo > qrow) p1 = 0.f;
      lsum[r] += p0 + p1;
      const int sw = ((rho >> 1) & 3) << 4;
      *(__bf16*)((char*)Pl + rho * 64 + ((llo * 2) ^ sw))      = (__bf16)p0;
      *(__bf16*)((char*)Pl + rho * 64 + ((llo * 2 + 32) ^ sw)) = (__bf16)p1;
    }
    bf16x8 pa = *(const bf16x8*)((const char*)Pl + llo * 64 +
                                 ((lhi * 16) ^ (((llo >> 1) & 3) << 4)));
#pragma unroll
    for (int n = 0; n < 8; n++) oacc[n] = MFMA(pa, vf[n], oacc[n]);
    if (t + 1 < t1) {   // prefetch next V into same regs
      const int kb2 = kb + 32;
#pragma unroll
      for (int n = 0; n < 8; n++)
        vf[n] = *(const bf16x8*)&Vg[(size_t)(n * 16 + llo) * SEQ + kb2 + lhi * 8];
    }
  }

#pragma unroll
  for (int r = 0; r < 4; r++) {
    float tsum = lsum[r];
    tsum += __shfl_xor(tsum, 1);
    tsum += __shfl_xor(tsum, 2);
    tsum += __shfl_xor(tsum, 4);
    tsum += __shfl_xor(tsum, 8);
    const int qrow = q0 + lhi * 4 + r;
    if (llo == 0) Ls[((size_t)p * NHEAD + h) * SEQ + qrow] = tsum;
#pragma unroll
    for (int n = 0; n < 8; n++)
      AOc[(size_t)qrow * HIDN + h * DH + n * 16 + llo] = oacc[n][r];
  }
}

// ---- merge split-KV partials, normalize, cast to bf16 ---------------------

__global__ __launch_bounds__(256) void k_norm(const float* __restrict__ A0,
                                              const float* __restrict__ A1,
                                              const float* __restrict__ Ls,
                                              __bf16* __restrict__ AO) {
  const int i = (blockIdx.x * 256 + threadIdx.x) * 4;  // 4M elems, f32x4
  const int q = i >> 11, h = (i & 2047) >> 7;
  const float inv = 1.f / (Ls[h * SEQ + q] + Ls[(NHEAD + h) * SEQ + q]);
  f32x4 a = *(const f32x4*)(A0 + i);
  f32x4 b = *(const f32x4*)(A1 + i);
#pragma unroll
  for (int j = 0; j < 4; j++) AO[i + j] = (__bf16)((a[j] + b[j]) * inv);
}

// ---------------------------------------------------------------------------

extern "C" void kernel_launch(void* const* d_in, const int* in_sizes, int n_in,
                              void* d_out, int out_size, void* d_ws, size_t ws_size,
                              hipStream_t stream) {
  const float* hidden = (const float*)d_in[0];
  const float* cosT   = (const float*)d_in[1];
  const float* sinT   = (const float*)d_in[2];
  // d_in[3] = mask (pure causal, computed analytically), d_in[4] = arange (unused)
  const float* WAq = (const float*)d_in[5];
  const float* WAk = (const float*)d_in[6];
  const float* WAv = (const float*)d_in[7];
  const float* WBq = (const float*)d_in[8];
  const float* WBk = (const float*)d_in[9];
  const float* WBv = (const float*)d_in[10];
  const float* Wo  = (const float*)d_in[11];
  float* out = (float*)d_out;

  // Workspace layout (lifetime-aliased, proven in R3), ~67.9 MB:
  //   [0)          hid_bf (8.39M)  -> AOf0 (16.78M) after build_qkv is done
  //   [8388608)    WallT  (5.77M)      (overlaid by AOf0)
  //   [14155776)   Pproj  (11.53M)     (first 2.6M overlaid by AOf0)
  //   [25690112)   WoT    (8.39M)      (live until final GEMM)
  //   [34078720)   Qb     (8.39M)  -> AO bf16 after attn is done
  //   [42467328)   Kb     (4.19M)
  //   [46661632)   Vt     (4.19M)
  //   [50855936)   AOf1   (16.78M)
  //   [67633152)   Ls     (0.26M)
  char* ws = (char*)d_ws;
  __bf16* hid_bf = (__bf16*)(ws);
  __bf16* WallT  = (__bf16*)(ws + 8388608);
  float*  Pproj  = (float*)(ws + 14155776);
  __bf16* WoT    = (__bf16*)(ws + 25690112);
  __bf16* Qb     = (__bf16*)(ws + 34078720);
  __bf16* Kb     = (__bf16*)(ws + 42467328);
  __bf16* Vt     = (__bf16*)(ws + 46661632);
  float*  AOf0   = (float*)(ws);
  float*  AOf1   = (float*)(ws + 50855936);
  float*  Ls     = (float*)(ws + 67633152);
  __bf16* AO     = (__bf16*)(ws + 34078720);  // aliases Qb (dead after attn)

  k_cvt_bf16<<<(SEQ * HIDN) / 256, 256, 0, stream>>>(hidden, hid_bf, SEQ * HIDN);
  k_pack_wall<<<(NCOLS * HIDN) / 256, 256, 0, stream>>>(WAq, WAk, WAv, WBq, WBk, WBv, WallT);
  k_pack_wo<<<dim3(64, 64), 256, 0, stream>>>(Wo, WoT);
  k_gemm_bt<<<dim3(NCOLS / 64, SEQ / 128), 256, 0, stream>>>(hid_bf, WallT, Pproj,
                                                             SEQ, NCOLS, HIDN);
  k_build_qkv<<<SEQ, 128, 0, stream>>>(Pproj, cosT, sinT, Qb, Kb, Vt);
  k_attn<<<1024, 256, 0, stream>>>(Qb, Kb, Vt, AOf0, AOf1, Ls);
  k_norm<<<(SEQ * HIDN / 4) / 256, 256, 0, stream>>>(AOf0, AOf1, Ls, AO);
  k_gemm_bt<<<dim3(HIDN / 64, SEQ / 128), 256, 0, stream>>>(AO, WoT, out,
                                                            SEQ, HIDN, HIDN);
}

// Round 6
// 183.568 us; speedup vs baseline: 1.7544x; 1.7544x over previous
//
#include <hip/hip_runtime.h>

// ---------------------------------------------------------------------------
// TPA attention, factorized to GQA flash attention.
// B=1, S=2048, HID=2048, H=16, KVH=8, D=128, QR=6, KR=2, VR=2
// ---------------------------------------------------------------------------

constexpr int SEQ   = 2048;
constexpr int HIDN  = 2048;
constexpr int NHEAD = 16;
constexpr int NKVH  = 8;
constexpr int DH    = 128;
constexpr int NCOLS = 1408;   // 96 Aq | 16 Ak | 16 Av | 768 Bq | 256 Bk | 256 Bv

typedef __bf16 bf16x8 __attribute__((ext_vector_type(8)));
typedef float  f32x4  __attribute__((ext_vector_type(4)));

#define MFMA(a, b, c) __builtin_amdgcn_mfma_f32_16x16x32_bf16((a), (b), (c), 0, 0, 0)

__device__ __forceinline__ void gload_lds16(const void* g, void* l) {
  __builtin_amdgcn_global_load_lds(
      (const __attribute__((address_space(1))) void*)g,
      (__attribute__((address_space(3))) void*)l, 16, 0, 0);
}

// ---- pack / convert -------------------------------------------------------

__global__ __launch_bounds__(256) void k_cvt_bf16(const float* __restrict__ x,
                                                  __bf16* __restrict__ y, int n) {
  int i = blockIdx.x * 256 + threadIdx.x;
  if (i < n) y[i] = (__bf16)x[i];
}

// W_all^T [1408][2048] bf16 so the GEMM B-operand reads K-contiguous rows.
__global__ __launch_bounds__(256) void k_pack_wall(
    const float* __restrict__ WAq, const float* __restrict__ WAk,
    const float* __restrict__ WAv, const float* __restrict__ WBq,
    const float* __restrict__ WBk, const float* __restrict__ WBv,
    __bf16* __restrict__ WT) {
  int i = blockIdx.x * 256 + threadIdx.x;  // i < 1408*2048
  int c = i >> 11, k = i & 2047;
  float v;
  if (c < 96)        v = WAq[k * 96 + c];
  else if (c < 112)  v = WAk[k * 16 + (c - 96)];
  else if (c < 128)  v = WAv[k * 16 + (c - 112)];
  else if (c < 896)  v = WBq[k * 768 + (c - 128)];
  else if (c < 1152) v = WBk[k * 256 + (c - 896)];
  else               v = WBv[k * 256 + (c - 1152)];
  WT[i] = (__bf16)v;
}

// Wo^T [2048][2048] bf16 via LDS tile transpose (coalesced both sides).
__global__ __launch_bounds__(256) void k_pack_wo(const float* __restrict__ Wo,
                                                 __bf16* __restrict__ WoT) {
  __shared__ float t[32][33];
  int bn = blockIdx.x * 32, bk = blockIdx.y * 32;
  int tx = threadIdx.x & 31, ty = threadIdx.x >> 5;  // ty 0..7
  for (int j = 0; j < 32; j += 8)
    t[ty + j][tx] = Wo[(size_t)(bk + ty + j) * HIDN + bn + tx];
  __syncthreads();
  for (int j = 0; j < 32; j += 8)
    WoT[(size_t)(bn + ty + j) * HIDN + bk + tx] = (__bf16)t[tx][ty + j];
}

// ---- GEMM: C[M][N] = A[M][K] * BT[N][K]^T, bf16 in, f32 out ---------------
// 128(M)x64(N) tile, 4 waves (2x2), BK=32, global_load_lds staging.

__global__ __launch_bounds__(256) void k_gemm_bt(const __bf16* __restrict__ A,
                                                 const __bf16* __restrict__ BT,
                                                 float* __restrict__ C,
                                                 int M, int N, int K) {
  __shared__ __bf16 As[4096];  // [128 rows][32 k] linear
  __shared__ __bf16 Bs[2048];  // [64 cols][32 k] linear
  const int tid = threadIdx.x;
  const int w = tid >> 6, lane = tid & 63;
  const int lhi = lane >> 4, llo = lane & 15;
  const int wr = w >> 1, wc = w & 1;
  const int brow = blockIdx.y * 128, bcol = blockIdx.x * 64;
  const int rA = lane >> 2, kA = (lane & 3) * 8;  // lane -> (row-in-seg, k-seg)

  f32x4 acc[4][2];
#pragma unroll
  for (int m = 0; m < 4; m++)
#pragma unroll
    for (int n = 0; n < 2; n++) acc[m][n] = (f32x4){0.f, 0.f, 0.f, 0.f};

  for (int k0 = 0; k0 < K; k0 += 32) {
#pragma unroll
    for (int i = 0; i < 2; i++) {
      int seg = w * 2 + i;           // 8 segs of 1KB for A
      int row = seg * 16 + rA;
      gload_lds16(A + (size_t)(brow + row) * K + k0 + kA, &As[seg * 512]);
    }
    gload_lds16(BT + (size_t)(bcol + w * 16 + rA) * K + k0 + kA, &Bs[w * 512]);
    __syncthreads();
    bf16x8 af[4], bfr[2];
#pragma unroll
    for (int m = 0; m < 4; m++)
      af[m] = *(const bf16x8*)&As[(wr * 64 + m * 16 + llo) * 32 + lhi * 8];
#pragma unroll
    for (int n = 0; n < 2; n++)
      bfr[n] = *(const bf16x8*)&Bs[(wc * 32 + n * 16 + llo) * 32 + lhi * 8];
#pragma unroll
    for (int m = 0; m < 4; m++)
#pragma unroll
      for (int n = 0; n < 2; n++) acc[m][n] = MFMA(af[m], bfr[n], acc[m][n]);
    __syncthreads();
  }
#pragma unroll
  for (int m = 0; m < 4; m++)
#pragma unroll
    for (int n = 0; n < 2; n++) {
      int r0 = brow + wr * 64 + m * 16 + lhi * 4;
      int c0 = bcol + wc * 32 + n * 16 + llo;
#pragma unroll
      for (int r = 0; r < 4; r++) C[(size_t)(r0 + r) * N + c0] = acc[m][n][r];
    }
}

// ---- build Q/K/Vt from projections (rope + rank contraction) --------------

__global__ __launch_bounds__(128) void k_build_qkv(const float* __restrict__ P,
                                                   const float* __restrict__ cosT,
                                                   const float* __restrict__ sinT,
                                                   __bf16* __restrict__ Qo,
                                                   __bf16* __restrict__ Ko,
                                                   __bf16* __restrict__ Vto) {
  const int q = blockIdx.x, d = threadIdx.x;  // 128 threads
  __shared__ float Ash[128];                  // Aq(96) | Ak(16) | Av(16)
  const float* row = P + (size_t)q * NCOLS;
  Ash[d] = row[d];
  __syncthreads();
  const int m2 = (d >> 1) * 2;
  const bool odd = d & 1;
  const float c = cosT[q * 64 + (d >> 1)];
  const float s = sinT[q * 64 + (d >> 1)];

  float qacc[16];
#pragma unroll
  for (int h = 0; h < 16; h++) qacc[h] = 0.f;
#pragma unroll
  for (int r = 0; r < 6; r++) {
    float xe = row[128 + r * 128 + m2];
    float xo = row[128 + r * 128 + m2 + 1];
    float br = odd ? (xe * s + xo * c) : (xe * c - xo * s);
#pragma unroll
    for (int h = 0; h < 16; h++) qacc[h] += Ash[h * 6 + r] * br;
  }
#pragma unroll
  for (int h = 0; h < 16; h++)
    Qo[((size_t)h * SEQ + q) * DH + d] = (__bf16)(qacc[h] * 0.08838834764831845f);

  float kacc[8];
#pragma unroll
  for (int g = 0; g < 8; g++) kacc[g] = 0.f;
#pragma unroll
  for (int ss = 0; ss < 2; ss++) {
    float xe = row[896 + ss * 128 + m2];
    float xo = row[896 + ss * 128 + m2 + 1];
    float bs = odd ? (xe * s + xo * c) : (xe * c - xo * s);
#pragma unroll
    for (int g = 0; g < 8; g++) kacc[g] += Ash[96 + g * 2 + ss] * bs;
  }
#pragma unroll
  for (int g = 0; g < 8; g++)
    Ko[((size_t)g * SEQ + q) * DH + d] = (__bf16)kacc[g];

  float vacc[8];
#pragma unroll
  for (int g = 0; g < 8; g++) vacc[g] = 0.f;
#pragma unroll
  for (int u = 0; u < 2; u++) {
    float vu = row[1152 + u * 128 + d];
#pragma unroll
    for (int g = 0; g < 8; g++) vacc[g] += Ash[112 + g * 2 + u] * vu;
  }
#pragma unroll
  for (int g = 0; g < 8; g++)
    Vto[((size_t)g * DH + d) * SEQ + q] = (__bf16)vacc[g];
}

// ---- flash attention, split-KV parts=2, LDS-staged, XCD-affine ------------
// R3 structure (best measured: staged global_load_lds shared by 4 lockstep
// waves, counted vmcnt(4)) + R5's proven XCD affinity (raw&7 = g => each
// XCD's L2 holds only its group's 1MB K/V; R3's 39MB HBM fetch -> ~10MB).
// Flat grid 1024: g=raw&7, j=raw>>3: bqi=31-(j>>2) (heavy-first within each
// XCD stripe, scheduler backfills), hh=(j>>1)&1, p=j&1, h=2g+hh.
// Fixed-max softmax (softcap bounds scores to (-50,50]) => split partials
// merge by pure addition in k_norm.

__global__ __launch_bounds__(256) void k_attn(const __bf16* __restrict__ Q,
                                              const __bf16* __restrict__ Kc,
                                              const __bf16* __restrict__ Vt,
                                              float* __restrict__ AOf0,
                                              float* __restrict__ AOf1,
                                              float* __restrict__ Ls) {
  const int raw = blockIdx.x;          // 0..1023
  const int g = raw & 7;               // XCD affinity
  const int j = raw >> 3;              // 0..127
  const int bqi = 31 - (j >> 2);       // heavy-first per XCD stripe
  const int hh = (j >> 1) & 1;
  const int p = j & 1;
  const int h = g * 2 + hh;
  const int w = threadIdx.x >> 6, lane = threadIdx.x & 63;
  const int lhi = lane >> 4, llo = lane & 15;
  const int q0 = bqi * 64 + w * 16;
  const int t0 = p * (bqi + 1), t1 = t0 + bqi + 1;  // half the causal tiles

  __shared__ __bf16 KVs[2][8192];    // 8KB K (32x128 swz) | 8KB V (128x32 swz)
  __shared__ __bf16 Plds[4][512];    // per-wave 16x32 P tile, swizzled

  const __bf16* Qh = Q  + (size_t)h * SEQ * DH;
  const __bf16* Kg = Kc + (size_t)g * SEQ * DH;
  const __bf16* Vg = Vt + (size_t)g * DH * SEQ;
  __bf16* Pl = Plds[w];
  float* AOc = p ? AOf1 : AOf0;

  bf16x8 aq[4];
#pragma unroll
  for (int c = 0; c < 4; c++)
    aq[c] = *(const bf16x8*)&Qh[(size_t)(q0 + llo) * DH + c * 32 + lhi * 8];

  f32x4 oacc[8];
  float lsum[4] = {0.f, 0.f, 0.f, 0.f};
#pragma unroll
  for (int n = 0; n < 8; n++) oacc[n] = (f32x4){0.f, 0.f, 0.f, 0.f};

  // stage one 32-key tile: waves 0-1 stage K (512 16B chunks, swizzled
  // source so linear LDS dest + swizzled read match), waves 2-3 stage V.
  auto stage = [&](int kb, int buf) {
    __bf16* L = KVs[buf];
    if (w < 2) {
#pragma unroll
      for (int u = 0; u < 4; u++) {
        int c = w * 256 + u * 64 + lane;
        int row = c >> 4, jj = c & 15;
        gload_lds16(Kg + (size_t)(kb + row) * DH + ((jj ^ (row & 7)) * 8),
                    L + (w * 256 + u * 64) * 8);
      }
    } else {
#pragma unroll
      for (int u = 0; u < 4; u++) {
        int c = (w - 2) * 256 + u * 64 + lane;
        int d = c >> 2, jj = c & 3;
        gload_lds16(Vg + (size_t)d * SEQ + kb + ((jj ^ ((d >> 1) & 3)) * 8),
                    L + 4096 + ((w - 2) * 256 + u * 64) * 8);
      }
    }
  };

  stage(t0 * 32, t0 & 1);
  for (int t = t0; t < t1; t++) {
    const int kb = t * 32;
    const int buf = t & 1;
    if (t + 1 < t1) {
      stage(kb + 32, buf ^ 1);
      asm volatile("s_waitcnt vmcnt(4)" ::: "memory");  // cur tile staged
    } else {
      asm volatile("s_waitcnt vmcnt(0)" ::: "memory");
    }
    __builtin_amdgcn_s_barrier();
    if (kb <= q0 + 15) {   // wave-uniform skip of fully-masked tiles
      const __bf16* Kl = KVs[buf];
      const __bf16* Vl = KVs[buf] + 4096;
      f32x4 s0 = {0.f, 0.f, 0.f, 0.f}, s1 = {0.f, 0.f, 0.f, 0.f};
#pragma unroll
      for (int c = 0; c < 4; c++) {
        const int row0 = llo, row1 = 16 + llo;
        bf16x8 k0 = *(const bf16x8*)((const char*)Kl + row0 * 256 +
                                     ((c * 64 + lhi * 16) ^ ((row0 & 7) << 4)));
        bf16x8 k1 = *(const bf16x8*)((const char*)Kl + row1 * 256 +
                                     ((c * 64 + lhi * 16) ^ ((row1 & 7) << 4)));
        s0 = MFMA(aq[c], k0, s0);
        s1 = MFMA(aq[c], k1, s1);
      }
#pragma unroll
      for (int r = 0; r < 4; r++) {
        const int qrow = q0 + lhi * 4 + r;
        const int rho = lhi * 4 + r;
        // w = exp(50*tanh(v/50)) = exp2(72.135 - 144.27/(e^{v/25}+1));
        // range [e^-50, e^50] — f32-safe, exact softmax after normalize.
        float t0e = exp2f(s0[r] * 0.057707802f);
        float t1e = exp2f(s1[r] * 0.057707802f);
        float p0 = exp2f(72.134752f - 144.269504f * __builtin_amdgcn_rcpf(t0e + 1.f));
        float p1 = exp2f(72.134752f - 144.269504f * __builtin_amdgcn_rcpf(t1e + 1.f));
        if (kb + llo > qrow) p0 = 0.f;
        if (kb + 16 + llo > qrow) p1 = 0.f;
        lsum[r] += p0 + p1;
        const int sw = ((rho >> 1) & 3) << 4;
        *(__bf16*)((char*)Pl + rho * 64 + ((llo * 2) ^ sw))      = (__bf16)p0;
        *(__bf16*)((char*)Pl + rho * 64 + ((llo * 2 + 32) ^ sw)) = (__bf16)p1;
      }
      bf16x8 pa = *(const bf16x8*)((const char*)Pl + llo * 64 +
                                   ((lhi * 16) ^ (((llo >> 1) & 3) << 4)));
#pragma unroll
      for (int n = 0; n < 8; n++) {
        const int d = n * 16 + llo;
        bf16x8 vf = *(const bf16x8*)((const char*)Vl + d * 64 +
                                     ((lhi * 16) ^ (((d >> 1) & 3) << 4)));
        oacc[n] = MFMA(pa, vf, oacc[n]);
      }
    }
    asm volatile("" ::: "memory");
    __builtin_amdgcn_s_barrier();
  }

#pragma unroll
  for (int r = 0; r < 4; r++) {
    float tsum = lsum[r];
    tsum += __shfl_xor(tsum, 1);
    tsum += __shfl_xor(tsum, 2);
    tsum += __shfl_xor(tsum, 4);
    tsum += __shfl_xor(tsum, 8);
    const int qrow = q0 + lhi * 4 + r;
    if (llo == 0) Ls[((size_t)p * NHEAD + h) * SEQ + qrow] = tsum;
#pragma unroll
    for (int n = 0; n < 8; n++)
      AOc[(size_t)qrow * HIDN + h * DH + n * 16 + llo] = oacc[n][r];
  }
}

// ---- merge split-KV partials, normalize, cast to bf16 ---------------------

__global__ __launch_bounds__(256) void k_norm(const float* __restrict__ A0,
                                              const float* __restrict__ A1,
                                              const float* __restrict__ Ls,
                                              __bf16* __restrict__ AO) {
  const int i = (blockIdx.x * 256 + threadIdx.x) * 4;  // 4M elems, f32x4
  const int q = i >> 11, h = (i & 2047) >> 7;
  const float inv = 1.f / (Ls[h * SEQ + q] + Ls[(NHEAD + h) * SEQ + q]);
  f32x4 a = *(const f32x4*)(A0 + i);
  f32x4 b = *(const f32x4*)(A1 + i);
#pragma unroll
  for (int j = 0; j < 4; j++) AO[i + j] = (__bf16)((a[j] + b[j]) * inv);
}

// ---------------------------------------------------------------------------

extern "C" void kernel_launch(void* const* d_in, const int* in_sizes, int n_in,
                              void* d_out, int out_size, void* d_ws, size_t ws_size,
                              hipStream_t stream) {
  const float* hidden = (const float*)d_in[0];
  const float* cosT   = (const float*)d_in[1];
  const float* sinT   = (const float*)d_in[2];
  // d_in[3] = mask (pure causal, computed analytically), d_in[4] = arange (unused)
  const float* WAq = (const float*)d_in[5];
  const float* WAk = (const float*)d_in[6];
  const float* WAv = (const float*)d_in[7];
  const float* WBq = (const float*)d_in[8];
  const float* WBk = (const float*)d_in[9];
  const float* WBv = (const float*)d_in[10];
  const float* Wo  = (const float*)d_in[11];
  float* out = (float*)d_out;

  // Workspace layout (lifetime-aliased, proven in R3), ~67.9 MB:
  //   [0)          hid_bf (8.39M)  -> AOf0 (16.78M) after build_qkv is done
  //   [8388608)    WallT  (5.77M)      (overlaid by AOf0)
  //   [14155776)   Pproj  (11.53M)     (first 2.6M overlaid by AOf0)
  //   [25690112)   WoT    (8.39M)      (live until final GEMM)
  //   [34078720)   Qb     (8.39M)  -> AO bf16 after attn is done
  //   [42467328)   Kb     (4.19M)
  //   [46661632)   Vt     (4.19M)
  //   [50855936)   AOf1   (16.78M)
  //   [67633152)   Ls     (0.26M)
  char* ws = (char*)d_ws;
  __bf16* hid_bf = (__bf16*)(ws);
  __bf16* WallT  = (__bf16*)(ws + 8388608);
  float*  Pproj  = (float*)(ws + 14155776);
  __bf16* WoT    = (__bf16*)(ws + 25690112);
  __bf16* Qb     = (__bf16*)(ws + 34078720);
  __bf16* Kb     = (__bf16*)(ws + 42467328);
  __bf16* Vt     = (__bf16*)(ws + 46661632);
  float*  AOf0   = (float*)(ws);
  float*  AOf1   = (float*)(ws + 50855936);
  float*  Ls     = (float*)(ws + 67633152);
  __bf16* AO     = (__bf16*)(ws + 34078720);  // aliases Qb (dead after attn)

  k_cvt_bf16<<<(SEQ * HIDN) / 256, 256, 0, stream>>>(hidden, hid_bf, SEQ * HIDN);
  k_pack_wall<<<(NCOLS * HIDN) / 256, 256, 0, stream>>>(WAq, WAk, WAv, WBq, WBk, WBv, WallT);
  k_pack_wo<<<dim3(64, 64), 256, 0, stream>>>(Wo, WoT);
  k_gemm_bt<<<dim3(NCOLS / 64, SEQ / 128), 256, 0, stream>>>(hid_bf, WallT, Pproj,
                                                             SEQ, NCOLS, HIDN);
  k_build_qkv<<<SEQ, 128, 0, stream>>>(Pproj, cosT, sinT, Qb, Kb, Vt);
  k_attn<<<1024, 256, 0, stream>>>(Qb, Kb, Vt, AOf0, AOf1, Ls);
  k_norm<<<(SEQ * HIDN / 4) / 256, 256, 0, stream>>>(AOf0, AOf1, Ls, AO);
  k_gemm_bt<<<dim3(HIDN / 64, SEQ / 128), 256, 0, stream>>>(AO, WoT, out,
                                                            SEQ, HIDN, HIDN);
}

// Round 7
// 169.776 us; speedup vs baseline: 1.8970x; 1.0812x over previous
//
#include <hip/hip_runtime.h>

// ---------------------------------------------------------------------------
// TPA attention, factorized to GQA flash attention.
// B=1, S=2048, HID=2048, H=16, KVH=8, D=128, QR=6, KR=2, VR=2
// ---------------------------------------------------------------------------

constexpr int SEQ   = 2048;
constexpr int HIDN  = 2048;
constexpr int NHEAD = 16;
constexpr int NKVH  = 8;
constexpr int DH    = 128;
constexpr int NCOLS = 1408;   // 96 Aq | 16 Ak | 16 Av | 768 Bq | 256 Bk | 256 Bv

typedef __bf16 bf16x8 __attribute__((ext_vector_type(8)));
typedef float  f32x4  __attribute__((ext_vector_type(4)));

#define MFMA(a, b, c) __builtin_amdgcn_mfma_f32_16x16x32_bf16((a), (b), (c), 0, 0, 0)

__device__ __forceinline__ void gload_lds16(const void* g, void* l) {
  __builtin_amdgcn_global_load_lds(
      (const __attribute__((address_space(1))) void*)g,
      (__attribute__((address_space(3))) void*)l, 16, 0, 0);
}

// ---- pack / convert -------------------------------------------------------

__global__ __launch_bounds__(256) void k_cvt_bf16(const float* __restrict__ x,
                                                  __bf16* __restrict__ y, int n) {
  int i = blockIdx.x * 256 + threadIdx.x;
  if (i < n) y[i] = (__bf16)x[i];
}

// W_all^T [1408][2048] bf16 so the GEMM B-operand reads K-contiguous rows.
__global__ __launch_bounds__(256) void k_pack_wall(
    const float* __restrict__ WAq, const float* __restrict__ WAk,
    const float* __restrict__ WAv, const float* __restrict__ WBq,
    const float* __restrict__ WBk, const float* __restrict__ WBv,
    __bf16* __restrict__ WT) {
  int i = blockIdx.x * 256 + threadIdx.x;  // i < 1408*2048
  int c = i >> 11, k = i & 2047;
  float v;
  if (c < 96)        v = WAq[k * 96 + c];
  else if (c < 112)  v = WAk[k * 16 + (c - 96)];
  else if (c < 128)  v = WAv[k * 16 + (c - 112)];
  else if (c < 896)  v = WBq[k * 768 + (c - 128)];
  else if (c < 1152) v = WBk[k * 256 + (c - 896)];
  else               v = WBv[k * 256 + (c - 1152)];
  WT[i] = (__bf16)v;
}

// Wo^T [2048][2048] bf16 via LDS tile transpose (coalesced both sides).
__global__ __launch_bounds__(256) void k_pack_wo(const float* __restrict__ Wo,
                                                 __bf16* __restrict__ WoT) {
  __shared__ float t[32][33];
  int bn = blockIdx.x * 32, bk = blockIdx.y * 32;
  int tx = threadIdx.x & 31, ty = threadIdx.x >> 5;  // ty 0..7
  for (int j = 0; j < 32; j += 8)
    t[ty + j][tx] = Wo[(size_t)(bk + ty + j) * HIDN + bn + tx];
  __syncthreads();
  for (int j = 0; j < 32; j += 8)
    WoT[(size_t)(bn + ty + j) * HIDN + bk + tx] = (__bf16)t[tx][ty + j];
}

// ---- GEMM: C[M][N] = A[M][K] * BT[N][K]^T, bf16 in, f32 out ---------------
// 128(M)x64(N) tile, 4 waves (2x2), BK=32. 2-phase double-buffered pipeline
// (T3-minimum): prologue stages tile 0; each iter {stage(t+1) -> other buf;
// compute(t); vmcnt(0)+barrier}. Prefetch lands under the 16-MFMA compute
// phase; ONE barrier per K-step (vs __syncthreads' serial drain-then-compute).
// WAR-safe: stage(t+1) targets the buffer whose compute finished at the
// previous iteration's barrier. XCD chunk-swizzle on linearized block id.

__global__ __launch_bounds__(256) void k_gemm_bt(const __bf16* __restrict__ A,
                                                 const __bf16* __restrict__ BT,
                                                 float* __restrict__ C,
                                                 int M, int N, int K) {
  __shared__ __bf16 As[2][4096];  // [buf][128 rows][32 k] linear
  __shared__ __bf16 Bs[2][2048];  // [buf][64 cols][32 k] linear
  const int tid = threadIdx.x;
  const int w = tid >> 6, lane = tid & 63;
  const int lhi = lane >> 4, llo = lane & 15;
  const int wr = w >> 1, wc = w & 1;

  // XCD chunk-swizzle (grid sizes 352/512 are divisible by 8: bijective).
  const int nx = gridDim.x;
  const int id = blockIdx.y * nx + blockIdx.x;
  const int cpx = (nx * gridDim.y) >> 3;
  const int sid = (id & 7) * cpx + (id >> 3);
  const int brow = (sid / nx) * 128, bcol = (sid % nx) * 64;

  const int rA = lane >> 2, kA = (lane & 3) * 8;  // lane -> (row-in-seg, k-seg)
  const int nt = K >> 5;

  f32x4 acc[4][2];
#pragma unroll
  for (int m = 0; m < 4; m++)
#pragma unroll
    for (int n = 0; n < 2; n++) acc[m][n] = (f32x4){0.f, 0.f, 0.f, 0.f};

  auto stage = [&](int t, int buf) {
    const int k0 = t * 32;
#pragma unroll
    for (int i = 0; i < 2; i++) {
      int seg = w * 2 + i;           // 8 segs of 1KB for A
      int row = seg * 16 + rA;
      gload_lds16(A + (size_t)(brow + row) * K + k0 + kA, &As[buf][seg * 512]);
    }
    gload_lds16(BT + (size_t)(bcol + w * 16 + rA) * K + k0 + kA, &Bs[buf][w * 512]);
  };

  stage(0, 0);
  asm volatile("s_waitcnt vmcnt(0)" ::: "memory");
  __builtin_amdgcn_s_barrier();

  for (int t = 0; t < nt; t++) {
    const int buf = t & 1;
    if (t + 1 < nt) stage(t + 1, buf ^ 1);   // prefetch under compute
    bf16x8 af[4], bfr[2];
#pragma unroll
    for (int m = 0; m < 4; m++)
      af[m] = *(const bf16x8*)&As[buf][(wr * 64 + m * 16 + llo) * 32 + lhi * 8];
#pragma unroll
    for (int n = 0; n < 2; n++)
      bfr[n] = *(const bf16x8*)&Bs[buf][(wc * 32 + n * 16 + llo) * 32 + lhi * 8];
#pragma unroll
    for (int m = 0; m < 4; m++)
#pragma unroll
      for (int n = 0; n < 2; n++) acc[m][n] = MFMA(af[m], bfr[n], acc[m][n]);
    asm volatile("s_waitcnt vmcnt(0)" ::: "memory");  // next tile landed
    __builtin_amdgcn_s_barrier();
  }

#pragma unroll
  for (int m = 0; m < 4; m++)
#pragma unroll
    for (int n = 0; n < 2; n++) {
      int r0 = brow + wr * 64 + m * 16 + lhi * 4;
      int c0 = bcol + wc * 32 + n * 16 + llo;
#pragma unroll
      for (int r = 0; r < 4; r++) C[(size_t)(r0 + r) * N + c0] = acc[m][n][r];
    }
}

// ---- build Q/K/Vt from projections (rope + rank contraction) --------------

__global__ __launch_bounds__(128) void k_build_qkv(const float* __restrict__ P,
                                                   const float* __restrict__ cosT,
                                                   const float* __restrict__ sinT,
                                                   __bf16* __restrict__ Qo,
                                                   __bf16* __restrict__ Ko,
                                                   __bf16* __restrict__ Vto) {
  const int q = blockIdx.x, d = threadIdx.x;  // 128 threads
  __shared__ float Ash[128];                  // Aq(96) | Ak(16) | Av(16)
  const float* row = P + (size_t)q * NCOLS;
  Ash[d] = row[d];
  __syncthreads();
  const int m2 = (d >> 1) * 2;
  const bool odd = d & 1;
  const float c = cosT[q * 64 + (d >> 1)];
  const float s = sinT[q * 64 + (d >> 1)];

  float qacc[16];
#pragma unroll
  for (int h = 0; h < 16; h++) qacc[h] = 0.f;
#pragma unroll
  for (int r = 0; r < 6; r++) {
    float xe = row[128 + r * 128 + m2];
    float xo = row[128 + r * 128 + m2 + 1];
    float br = odd ? (xe * s + xo * c) : (xe * c - xo * s);
#pragma unroll
    for (int h = 0; h < 16; h++) qacc[h] += Ash[h * 6 + r] * br;
  }
#pragma unroll
  for (int h = 0; h < 16; h++)
    Qo[((size_t)h * SEQ + q) * DH + d] = (__bf16)(qacc[h] * 0.08838834764831845f);

  float kacc[8];
#pragma unroll
  for (int g = 0; g < 8; g++) kacc[g] = 0.f;
#pragma unroll
  for (int ss = 0; ss < 2; ss++) {
    float xe = row[896 + ss * 128 + m2];
    float xo = row[896 + ss * 128 + m2 + 1];
    float bs = odd ? (xe * s + xo * c) : (xe * c - xo * s);
#pragma unroll
    for (int g = 0; g < 8; g++) kacc[g] += Ash[96 + g * 2 + ss] * bs;
  }
#pragma unroll
  for (int g = 0; g < 8; g++)
    Ko[((size_t)g * SEQ + q) * DH + d] = (__bf16)kacc[g];

  float vacc[8];
#pragma unroll
  for (int g = 0; g < 8; g++) vacc[g] = 0.f;
#pragma unroll
  for (int u = 0; u < 2; u++) {
    float vu = row[1152 + u * 128 + d];
#pragma unroll
    for (int g = 0; g < 8; g++) vacc[g] += Ash[112 + g * 2 + u] * vu;
  }
#pragma unroll
  for (int g = 0; g < 8; g++)
    Vto[((size_t)g * DH + d) * SEQ + q] = (__bf16)vacc[g];
}

// ---- flash attention, split-KV parts=2, LDS-staged, XCD-affine ------------
// (unchanged from R6: 55.5µs, FETCH 8.2MB — staged global_load_lds shared by
// 4 lockstep waves, counted vmcnt(4), XCD affinity raw&7 = g.)

__global__ __launch_bounds__(256) void k_attn(const __bf16* __restrict__ Q,
                                              const __bf16* __restrict__ Kc,
                                              const __bf16* __restrict__ Vt,
                                              float* __restrict__ AOf0,
                                              float* __restrict__ AOf1,
                                              float* __restrict__ Ls) {
  const int raw = blockIdx.x;          // 0..1023
  const int g = raw & 7;               // XCD affinity
  const int j = raw >> 3;              // 0..127
  const int bqi = 31 - (j >> 2);       // heavy-first per XCD stripe
  const int hh = (j >> 1) & 1;
  const int p = j & 1;
  const int h = g * 2 + hh;
  const int w = threadIdx.x >> 6, lane = threadIdx.x & 63;
  const int lhi = lane >> 4, llo = lane & 15;
  const int q0 = bqi * 64 + w * 16;
  const int t0 = p * (bqi + 1), t1 = t0 + bqi + 1;  // half the causal tiles

  __shared__ __bf16 KVs[2][8192];    // 8KB K (32x128 swz) | 8KB V (128x32 swz)
  __shared__ __bf16 Plds[4][512];    // per-wave 16x32 P tile, swizzled

  const __bf16* Qh = Q  + (size_t)h * SEQ * DH;
  const __bf16* Kg = Kc + (size_t)g * SEQ * DH;
  const __bf16* Vg = Vt + (size_t)g * DH * SEQ;
  __bf16* Pl = Plds[w];
  float* AOc = p ? AOf1 : AOf0;

  bf16x8 aq[4];
#pragma unroll
  for (int c = 0; c < 4; c++)
    aq[c] = *(const bf16x8*)&Qh[(size_t)(q0 + llo) * DH + c * 32 + lhi * 8];

  f32x4 oacc[8];
  float lsum[4] = {0.f, 0.f, 0.f, 0.f};
#pragma unroll
  for (int n = 0; n < 8; n++) oacc[n] = (f32x4){0.f, 0.f, 0.f, 0.f};

  // stage one 32-key tile: waves 0-1 stage K (512 16B chunks, swizzled
  // source so linear LDS dest + swizzled read match), waves 2-3 stage V.
  auto stage = [&](int kb, int buf) {
    __bf16* L = KVs[buf];
    if (w < 2) {
#pragma unroll
      for (int u = 0; u < 4; u++) {
        int c = w * 256 + u * 64 + lane;
        int row = c >> 4, jj = c & 15;
        gload_lds16(Kg + (size_t)(kb + row) * DH + ((jj ^ (row & 7)) * 8),
                    L + (w * 256 + u * 64) * 8);
      }
    } else {
#pragma unroll
      for (int u = 0; u < 4; u++) {
        int c = (w - 2) * 256 + u * 64 + lane;
        int d = c >> 2, jj = c & 3;
        gload_lds16(Vg + (size_t)d * SEQ + kb + ((jj ^ ((d >> 1) & 3)) * 8),
                    L + 4096 + ((w - 2) * 256 + u * 64) * 8);
      }
    }
  };

  stage(t0 * 32, t0 & 1);
  for (int t = t0; t < t1; t++) {
    const int kb = t * 32;
    const int buf = t & 1;
    if (t + 1 < t1) {
      stage(kb + 32, buf ^ 1);
      asm volatile("s_waitcnt vmcnt(4)" ::: "memory");  // cur tile staged
    } else {
      asm volatile("s_waitcnt vmcnt(0)" ::: "memory");
    }
    __builtin_amdgcn_s_barrier();
    if (kb <= q0 + 15) {   // wave-uniform skip of fully-masked tiles
      const __bf16* Kl = KVs[buf];
      const __bf16* Vl = KVs[buf] + 4096;
      f32x4 s0 = {0.f, 0.f, 0.f, 0.f}, s1 = {0.f, 0.f, 0.f, 0.f};
#pragma unroll
      for (int c = 0; c < 4; c++) {
        const int row0 = llo, row1 = 16 + llo;
        bf16x8 k0 = *(const bf16x8*)((const char*)Kl + row0 * 256 +
                                     ((c * 64 + lhi * 16) ^ ((row0 & 7) << 4)));
        bf16x8 k1 = *(const bf16x8*)((const char*)Kl + row1 * 256 +
                                     ((c * 64 + lhi * 16) ^ ((row1 & 7) << 4)));
        s0 = MFMA(aq[c], k0, s0);
        s1 = MFMA(aq[c], k1, s1);
      }
#pragma unroll
      for (int r = 0; r < 4; r++) {
        const int qrow = q0 + lhi * 4 + r;
        const int rho = lhi * 4 + r;
        // w = exp(50*tanh(v/50)) = exp2(72.135 - 144.27/(e^{v/25}+1));
        // range [e^-50, e^50] — f32-safe, exact softmax after normalize.
        float t0e = exp2f(s0[r] * 0.057707802f);
        float t1e = exp2f(s1[r] * 0.057707802f);
        float p0 = exp2f(72.134752f - 144.269504f * __builtin_amdgcn_rcpf(t0e + 1.f));
        float p1 = exp2f(72.134752f - 144.269504f * __builtin_amdgcn_rcpf(t1e + 1.f));
        if (kb + llo > qrow) p0 = 0.f;
        if (kb + 16 + llo > qrow) p1 = 0.f;
        lsum[r] += p0 + p1;
        const int sw = ((rho >> 1) & 3) << 4;
        *(__bf16*)((char*)Pl + rho * 64 + ((llo * 2) ^ sw))      = (__bf16)p0;
        *(__bf16*)((char*)Pl + rho * 64 + ((llo * 2 + 32) ^ sw)) = (__bf16)p1;
      }
      bf16x8 pa = *(const bf16x8*)((const char*)Pl + llo * 64 +
                                   ((lhi * 16) ^ (((llo >> 1) & 3) << 4)));
#pragma unroll
      for (int n = 0; n < 8; n++) {
        const int d = n * 16 + llo;
        bf16x8 vf = *(const bf16x8*)((const char*)Vl + d * 64 +
                                     ((lhi * 16) ^ (((d >> 1) & 3) << 4)));
        oacc[n] = MFMA(pa, vf, oacc[n]);
      }
    }
    asm volatile("" ::: "memory");
    __builtin_amdgcn_s_barrier();
  }

#pragma unroll
  for (int r = 0; r < 4; r++) {
    float tsum = lsum[r];
    tsum += __shfl_xor(tsum, 1);
    tsum += __shfl_xor(tsum, 2);
    tsum += __shfl_xor(tsum, 4);
    tsum += __shfl_xor(tsum, 8);
    const int qrow = q0 + lhi * 4 + r;
    if (llo == 0) Ls[((size_t)p * NHEAD + h) * SEQ + qrow] = tsum;
#pragma unroll
    for (int n = 0; n < 8; n++)
      AOc[(size_t)qrow * HIDN + h * DH + n * 16 + llo] = oacc[n][r];
  }
}

// ---- merge split-KV partials, normalize, cast to bf16 ---------------------

__global__ __launch_bounds__(256) void k_norm(const float* __restrict__ A0,
                                              const float* __restrict__ A1,
                                              const float* __restrict__ Ls,
                                              __bf16* __restrict__ AO) {
  const int i = (blockIdx.x * 256 + threadIdx.x) * 4;  // 4M elems, f32x4
  const int q = i >> 11, h = (i & 2047) >> 7;
  const float inv = 1.f / (Ls[h * SEQ + q] + Ls[(NHEAD + h) * SEQ + q]);
  f32x4 a = *(const f32x4*)(A0 + i);
  f32x4 b = *(const f32x4*)(A1 + i);
#pragma unroll
  for (int j = 0; j < 4; j++) AO[i + j] = (__bf16)((a[j] + b[j]) * inv);
}

// ---------------------------------------------------------------------------

extern "C" void kernel_launch(void* const* d_in, const int* in_sizes, int n_in,
                              void* d_out, int out_size, void* d_ws, size_t ws_size,
                              hipStream_t stream) {
  const float* hidden = (const float*)d_in[0];
  const float* cosT   = (const float*)d_in[1];
  const float* sinT   = (const float*)d_in[2];
  // d_in[3] = mask (pure causal, computed analytically), d_in[4] = arange (unused)
  const float* WAq = (const float*)d_in[5];
  const float* WAk = (const float*)d_in[6];
  const float* WAv = (const float*)d_in[7];
  const float* WBq = (const float*)d_in[8];
  const float* WBk = (const float*)d_in[9];
  const float* WBv = (const float*)d_in[10];
  const float* Wo  = (const float*)d_in[11];
  float* out = (float*)d_out;

  // Workspace layout (lifetime-aliased, proven in R3), ~67.9 MB:
  //   [0)          hid_bf (8.39M)  -> AOf0 (16.78M) after build_qkv is done
  //   [8388608)    WallT  (5.77M)      (overlaid by AOf0)
  //   [14155776)   Pproj  (11.53M)     (first 2.6M overlaid by AOf0)
  //   [25690112)   WoT    (8.39M)      (live until final GEMM)
  //   [34078720)   Qb     (8.39M)  -> AO bf16 after attn is done
  //   [42467328)   Kb     (4.19M)
  //   [46661632)   Vt     (4.19M)
  //   [50855936)   AOf1   (16.78M)
  //   [67633152)   Ls     (0.26M)
  char* ws = (char*)d_ws;
  __bf16* hid_bf = (__bf16*)(ws);
  __bf16* WallT  = (__bf16*)(ws + 8388608);
  float*  Pproj  = (float*)(ws + 14155776);
  __bf16* WoT    = (__bf16*)(ws + 25690112);
  __bf16* Qb     = (__bf16*)(ws + 34078720);
  __bf16* Kb     = (__bf16*)(ws + 42467328);
  __bf16* Vt     = (__bf16*)(ws + 46661632);
  float*  AOf0   = (float*)(ws);
  float*  AOf1   = (float*)(ws + 50855936);
  float*  Ls     = (float*)(ws + 67633152);
  __bf16* AO     = (__bf16*)(ws + 34078720);  // aliases Qb (dead after attn)

  k_cvt_bf16<<<(SEQ * HIDN) / 256, 256, 0, stream>>>(hidden, hid_bf, SEQ * HIDN);
  k_pack_wall<<<(NCOLS * HIDN) / 256, 256, 0, stream>>>(WAq, WAk, WAv, WBq, WBk, WBv, WallT);
  k_pack_wo<<<dim3(64, 64), 256, 0, stream>>>(Wo, WoT);
  k_gemm_bt<<<dim3(NCOLS / 64, SEQ / 128), 256, 0, stream>>>(hid_bf, WallT, Pproj,
                                                             SEQ, NCOLS, HIDN);
  k_build_qkv<<<SEQ, 128, 0, stream>>>(Pproj, cosT, sinT, Qb, Kb, Vt);
  k_attn<<<1024, 256, 0, stream>>>(Qb, Kb, Vt, AOf0, AOf1, Ls);
  k_norm<<<(SEQ * HIDN / 4) / 256, 256, 0, stream>>>(AOf0, AOf1, Ls, AO);
  k_gemm_bt<<<dim3(HIDN / 64, SEQ / 128), 256, 0, stream>>>(AO, WoT, out,
                                                            SEQ, HIDN, HIDN);
}